// Round 4
// baseline (274.527 us; speedup 1.0000x reference)
//
#include <hip/hip_runtime.h>
#include <hip/hip_bf16.h>
#include <math.h>

#define BB 4096
#define PP 512
#define WDT 10

typedef short short8 __attribute__((ext_vector_type(8)));
typedef float floatx4 __attribute__((ext_vector_type(4)));

__device__ __forceinline__ short f2bf(float f) {
    __hip_bfloat16 h = __float2bfloat16(f);   // RNE
    return __builtin_bit_cast(short, h);
}

// tanh(x) = 1 - 2/(exp2(2*log2e*x)+1); inf-safe without clamps.
__device__ __forceinline__ float fast_tanh(float x) {
    float e = __builtin_amdgcn_exp2f(x * 2.8853900817779268f);
    return 1.0f - 2.0f * __builtin_amdgcn_rcpf(e + 1.0f);
}

__global__ __launch_bounds__(256, 2) void frc_2b_kernel(
    const float* __restrict__ invar,    // [B,P,5]
    const float* __restrict__ vectors,  // [B,P,9]
    const float* __restrict__ w1_0,     // [5,10]
    const float* __restrict__ b1_0,     // [10]
    const float* __restrict__ w1_1,     // [10,10]
    const float* __restrict__ b1_1,     // [10]
    const float* __restrict__ lin0_w,   // [3,10]
    const float* __restrict__ na0_b,    // [10]
    const float* __restrict__ lin1_w,   // [10,10]
    const float* __restrict__ na1_b,    // [10]
    const float* __restrict__ final_w,  // [10,1]
    float* __restrict__ out)            // [B,3]
{
    const int b    = blockIdx.x;
    const int tid  = threadIdx.x;
    const int lane = tid & 63;
    const int wid  = tid >> 6;
    const int col  = lane & 15;   // MFMA col (output dim w) / A-row (pair)
    const int grp  = lane >> 4;   // lane group: k-slice 8*grp..8*grp+7, D-rows 4*grp..+3

    const float k3sq  = 0.33333333333333333f;   // (1/sqrt3)^2
    const float k3k10 = 0.18257418583505536f;   // 1/sqrt(30)
    const float k10   = 0.31622776601683794f;   // 1/sqrt(10)

    // Wave-private LDS scratch: 4 regions x 16 rows x 40 bf16 (stride 40 ->
    // 80B rows: 16B-aligned b128 reads, (r,r+8) 2-way banks = free).
    __shared__ __align__(16) short lds[4][4][640];
    short* ylds = lds[wid][0];
    short* x0l0 = lds[wid][1];
    short* x0l1 = lds[wid][2];
    short* x0l2 = lds[wid][3];

    // Zero all 4 regions once: MFMA K/N padding reads must see exact zeros.
    {
        int* zi = (int*)ylds;   // 4*640 shorts = 1280 ints = 64 lanes * 20
        #pragma unroll
        for (int i = 0; i < 20; ++i) zi[lane + i * 64] = 0;
    }
    __builtin_amdgcn_sched_barrier(0);

    const bool colv = (col < WDT);
    const int  colc = colv ? col : 0;

    // per-lane scalars, zero-padded for col >= 10
    const float b0c  = colv ? b1_0[colc]  : 0.f;
    const float b1c  = colv ? b1_1[colc]  : 0.f;
    const float na0c = colv ? na0_b[colc] : 0.f;
    const float na1c = colv ? na1_b[colc] : 0.f;
    const float fwc  = colv ? final_w[colc] * k10 : 0.f;

    // B-fragments: B[k][col], lane holds k = 8*grp + i. All weights -> 16 VGPRs.
    short8 B10, B11, BL0, BL1;
    #pragma unroll
    for (int i = 0; i < 8; ++i) {
        const int k = grp * 8 + i;
        B10[i] = (colv && k < 5)  ? f2bf(w1_0[(k < 5 ? k : 4) * WDT + colc])   : (short)0;
        B11[i] = (colv && k < 10) ? f2bf(w1_1[(k < 10 ? k : 9) * WDT + colc])  : (short)0;
        BL0[i] = (colv && k < 3)  ? f2bf(lin0_w[(k < 3 ? k : 2) * WDT + colc]) : (short)0;
        BL1[i] = (colv && k < 10) ? f2bf(lin1_w[(k < 10 ? k : 9) * WDT + colc]): (short)0;
    }

    const floatx4 zz = {0.f, 0.f, 0.f, 0.f};
    float acc0 = 0.f, acc1 = 0.f, acc2 = 0.f;

    for (int it = 0; it < 8; ++it) {
        const int p = it * 64 + wid * 16 + col;     // this lane's A-row pair
        const float* iv = invar   + ((size_t)b * PP + p) * 5;
        const float* vv = vectors + ((size_t)b * PP + p) * 9;
        const bool g0 = (grp == 0);

        // A-fragment, scalar L1: rows=pairs, k=5 inputs (only grp 0 nonzero)
        short8 A1;
        A1[0] = g0 ? f2bf(iv[0]) : (short)0;
        A1[1] = g0 ? f2bf(iv[1]) : (short)0;
        A1[2] = g0 ? f2bf(iv[2]) : (short)0;
        A1[3] = g0 ? f2bf(iv[3]) : (short)0;
        A1[4] = g0 ? f2bf(iv[4]) : (short)0;
        A1[5] = 0; A1[6] = 0; A1[7] = 0;

        // A-fragments for lin0 (k = 3 irreps), one per vector component
        short8 AV0, AV1, AV2;
        AV0[0] = g0 ? f2bf(vv[0]) : (short)0;
        AV0[1] = g0 ? f2bf(vv[3]) : (short)0;
        AV0[2] = g0 ? f2bf(vv[6]) : (short)0;
        AV1[0] = g0 ? f2bf(vv[1]) : (short)0;
        AV1[1] = g0 ? f2bf(vv[4]) : (short)0;
        AV1[2] = g0 ? f2bf(vv[7]) : (short)0;
        AV2[0] = g0 ? f2bf(vv[2]) : (short)0;
        AV2[1] = g0 ? f2bf(vv[5]) : (short)0;
        AV2[2] = g0 ? f2bf(vv[8]) : (short)0;
        #pragma unroll
        for (int i = 3; i < 8; ++i) { AV0[i] = 0; AV1[i] = 0; AV2[i] = 0; }

        // ---- scalar branch L1: D1[pair][w] = in5 @ w1_0
        floatx4 D1 = __builtin_amdgcn_mfma_f32_16x16x32_bf16(A1, B10, zz, 0, 0, 0);
        // y = relu(D1 + b), write transposed into ylds[pair][w]
        ylds[(4 * grp + 0) * 40 + col] = f2bf(fmaxf(D1[0] + b0c, 0.f));
        ylds[(4 * grp + 1) * 40 + col] = f2bf(fmaxf(D1[1] + b0c, 0.f));
        ylds[(4 * grp + 2) * 40 + col] = f2bf(fmaxf(D1[2] + b0c, 0.f));
        ylds[(4 * grp + 3) * 40 + col] = f2bf(fmaxf(D1[3] + b0c, 0.f));
        __builtin_amdgcn_sched_barrier(0);
        // A2[pair][k=w of y]
        const short8 A2 = *(const short8*)(ylds + col * 40 + grp * 8);
        floatx4 D2 = __builtin_amdgcn_mfma_f32_16x16x32_bf16(A2, B11, zz, 0, 0, 0);
        const float y2r0 = fmaxf(D2[0] + b1c, 0.f);
        const float y2r1 = fmaxf(D2[1] + b1c, 0.f);
        const float y2r2 = fmaxf(D2[2] + b1c, 0.f);
        const float y2r3 = fmaxf(D2[3] + b1c, 0.f);

        // ---- equivariant stage 1: c_comp[pair][w] = v @ lin0_w (unscaled)
        floatx4 C0 = __builtin_amdgcn_mfma_f32_16x16x32_bf16(AV0, BL0, zz, 0, 0, 0);
        floatx4 C1 = __builtin_amdgcn_mfma_f32_16x16x32_bf16(AV1, BL0, zz, 0, 0, 0);
        floatx4 C2 = __builtin_amdgcn_mfma_f32_16x16x32_bf16(AV2, BL0, zz, 0, 0, 0);
        #pragma unroll
        for (int r = 0; r < 4; ++r) {
            float c0 = C0[r], c1 = C1[r], c2 = C2[r];
            float n2u   = fmaf(c0, c0, fmaf(c1, c1, c2 * c2));
            float m     = fmaxf(n2u * k3sq, 1e-12f);
            float inv_n = __builtin_amdgcn_rsqf(m);
            float n     = m * inv_n;
            float t     = fast_tanh(n + na0c);
            float f     = t * inv_n * k3k10;   // folds 1/sqrt3 * 1/sqrt10
            const int a = (4 * grp + r) * 40 + col;
            x0l0[a] = f2bf(c0 * f);
            x0l1[a] = f2bf(c1 * f);
            x0l2[a] = f2bf(c2 * f);
        }
        __builtin_amdgcn_sched_barrier(0);

        // ---- equivariant stage 2: E_comp[pair][w] = x0 @ lin1_w (== ref y2v)
        const int ra = col * 40 + grp * 8;
        const short8 A30 = *(const short8*)(x0l0 + ra);
        const short8 A31 = *(const short8*)(x0l1 + ra);
        const short8 A32 = *(const short8*)(x0l2 + ra);
        floatx4 E0 = __builtin_amdgcn_mfma_f32_16x16x32_bf16(A30, BL1, zz, 0, 0, 0);
        floatx4 E1 = __builtin_amdgcn_mfma_f32_16x16x32_bf16(A31, BL1, zz, 0, 0, 0);
        floatx4 E2 = __builtin_amdgcn_mfma_f32_16x16x32_bf16(A32, BL1, zz, 0, 0, 0);
        const float y2r[4] = {y2r0, y2r1, y2r2, y2r3};
        #pragma unroll
        for (int r = 0; r < 4; ++r) {
            float c0 = E0[r], c1 = E1[r], c2 = E2[r];
            float m     = fmaxf(fmaf(c0, c0, fmaf(c1, c1, c2 * c2)), 1e-12f);
            float inv_n = __builtin_amdgcn_rsqf(m);
            float n     = m * inv_n;
            float t     = fast_tanh(n + na1c);
            float g     = y2r[r] * t * inv_n * fwc;   // fwc==0 for col>=10
            acc0 = fmaf(c0, g, acc0);
            acc1 = fmaf(c1, g, acc1);
            acc2 = fmaf(c2, g, acc2);
        }
        __builtin_amdgcn_sched_barrier(0);   // keep next iter's LDS writes after reads
    }

    // ---- block reduction: every lane holds a partial of out[b][*]
    #pragma unroll
    for (int off = 32; off > 0; off >>= 1) {
        acc0 += __shfl_down(acc0, off, 64);
        acc1 += __shfl_down(acc1, off, 64);
        acc2 += __shfl_down(acc2, off, 64);
    }
    __shared__ float red[4][3];
    if ((tid & 63) == 0) {
        red[wid][0] = acc0; red[wid][1] = acc1; red[wid][2] = acc2;
    }
    __syncthreads();
    if (tid == 0) {
        float r0 = 0.f, r1 = 0.f, r2 = 0.f;
        #pragma unroll
        for (int wv = 0; wv < 4; ++wv) { r0 += red[wv][0]; r1 += red[wv][1]; r2 += red[wv][2]; }
        out[b * 3 + 0] = r0;
        out[b * 3 + 1] = r1;
        out[b * 3 + 2] = r2;
    }
}

extern "C" void kernel_launch(void* const* d_in, const int* in_sizes, int n_in,
                              void* d_out, int out_size, void* d_ws, size_t ws_size,
                              hipStream_t stream) {
    const float* invar   = (const float*)d_in[0];
    const float* vectors = (const float*)d_in[1];
    const float* w1_0    = (const float*)d_in[2];
    const float* b1_0    = (const float*)d_in[3];
    const float* w1_1    = (const float*)d_in[4];
    const float* b1_1    = (const float*)d_in[5];
    const float* lin0_w  = (const float*)d_in[6];
    const float* na0_b   = (const float*)d_in[7];
    const float* lin1_w  = (const float*)d_in[8];
    const float* na1_b   = (const float*)d_in[9];
    const float* final_w = (const float*)d_in[10];
    float* out = (float*)d_out;

    frc_2b_kernel<<<BB, 256, 0, stream>>>(invar, vectors, w1_0, b1_0, w1_1, b1_1,
                                          lin0_w, na0_b, lin1_w, na1_b, final_w, out);
}

// Round 5
// 178.513 us; speedup vs baseline: 1.5379x; 1.5379x over previous
//
#include <hip/hip_runtime.h>
#include <math.h>

#define BB 4096
#define PP 512
#define WDT 10

typedef float float4v __attribute__((ext_vector_type(4)));

// tanh(x) = 1 - 2/(exp2(2*log2e*x)+1); inf-safe without clamps.
__device__ __forceinline__ float fast_tanh(float x) {
    float e = __builtin_amdgcn_exp2f(x * 2.8853900817779268f); // v_exp_f32
    return 1.0f - 2.0f * __builtin_amdgcn_rcpf(e + 1.0f);      // v_rcp_f32
}

// LDS weight layout (floats):
//   [0,80)    W1T: 10 rows x 8  : w1_0[0..4][j], b1_0[j], 0, 0
//   [80,200)  W2T: 10 rows x 12 : w1_1[0..9][j], b1_1[j], 0
//   [200,240) L0T: 10 rows x 4  : lin0[0..2][j], 0
//   [240,360) L1T: 10 rows x 12 : lin1[0..9][j], 0, 0
//   [360,370) na0_b ; [370,380) na1_b ; [380,390) final_w * 1/sqrt(10)
__global__ __launch_bounds__(512) void frc_2b_kernel(
    const float* __restrict__ invar,    // [B,P,5]
    const float* __restrict__ vectors,  // [B,P,9]
    const float* __restrict__ w1_0,     // [5,10]
    const float* __restrict__ b1_0,     // [10]
    const float* __restrict__ w1_1,     // [10,10]
    const float* __restrict__ b1_1,     // [10]
    const float* __restrict__ lin0_w,   // [3,10]
    const float* __restrict__ na0_b,    // [10]
    const float* __restrict__ lin1_w,   // [10,10]
    const float* __restrict__ na1_b,    // [10]
    const float* __restrict__ final_w,  // [10,1]
    float* __restrict__ out)            // [B,3]
{
    __shared__ __align__(16) float wl[392];
    __shared__ float red[8][3];

    const int b   = blockIdx.x;
    const int tid = threadIdx.x;

    // ---- stage all weights (transposed, padded, bias-folded) into LDS once
    if (tid < 392) {
        int t = tid; float val = 0.f;
        if (t < 80) {
            int j = t >> 3, i = t & 7;
            val = (i < 5) ? w1_0[i * WDT + j] : (i == 5 ? b1_0[j] : 0.f);
        } else if (t < 200) {
            int u = t - 80; int j = u / 12, i = u - 12 * j;
            val = (i < 10) ? w1_1[i * WDT + j] : (i == 10 ? b1_1[j] : 0.f);
        } else if (t < 240) {
            int u = t - 200; int j = u >> 2, i = u & 3;
            val = (i < 3) ? lin0_w[i * WDT + j] : 0.f;
        } else if (t < 360) {
            int u = t - 240; int j = u / 12, i = u - 12 * j;
            val = (i < 10) ? lin1_w[i * WDT + j] : 0.f;
        } else if (t < 370) {
            val = na0_b[t - 360];
        } else if (t < 380) {
            val = na1_b[t - 370];
        } else if (t < 390) {
            val = final_w[t - 380] * 0.31622776601683794f;  // fold 1/sqrt(10)
        }
        wl[t] = val;
    }

    // ---- issue this thread's input loads early (overlap with staging)
    const float* iv = invar   + ((size_t)b * PP + tid) * 5;
    const float* vv = vectors + ((size_t)b * PP + tid) * 9;
    float in0 = iv[0], in1 = iv[1], in2 = iv[2], in3 = iv[3], in4 = iv[4];
    float v0 = vv[0], v1 = vv[1], v2 = vv[2], v3 = vv[3], v4 = vv[4],
          v5 = vv[5], v6 = vv[6], v7 = vv[7], v8 = vv[8];

    __syncthreads();

    const float k3sq  = 0.33333333333333333f;   // (1/sqrt3)^2
    const float k3k10 = 0.18257418583505536f;   // 1/sqrt(30)

    // ---- scalar branch L1: y = relu(in5 @ w1_0 + b)
    float y[WDT];
    #pragma unroll
    for (int j = 0; j < WDT; ++j) {
        float4v wa = *(const float4v*)(wl + 8 * j);
        float4v wb = *(const float4v*)(wl + 8 * j + 4);
        float a = wb[1];                       // bias
        a = fmaf(in0, wa[0], a); a = fmaf(in1, wa[1], a);
        a = fmaf(in2, wa[2], a); a = fmaf(in3, wa[3], a);
        a = fmaf(in4, wb[0], a);
        y[j] = fmaxf(a, 0.f);
    }

    // ---- scalar branch L2: y2g = relu(y @ w1_1 + b)
    float y2g[WDT];
    #pragma unroll
    for (int j = 0; j < WDT; ++j) {
        const float* r = wl + 80 + 12 * j;
        float4v a0 = *(const float4v*)(r);
        float4v a1 = *(const float4v*)(r + 4);
        float4v a2 = *(const float4v*)(r + 8);
        float a = a2[2];                       // bias
        a = fmaf(y[0], a0[0], a); a = fmaf(y[1], a0[1], a);
        a = fmaf(y[2], a0[2], a); a = fmaf(y[3], a0[3], a);
        a = fmaf(y[4], a1[0], a); a = fmaf(y[5], a1[1], a);
        a = fmaf(y[6], a1[2], a); a = fmaf(y[7], a1[3], a);
        a = fmaf(y[8], a2[0], a); a = fmaf(y[9], a2[1], a);
        y2g[j] = fmaxf(a, 0.f);
    }

    // ---- equivariant stage 1: lin0 + NormActivation
    // x0 stored with 1/sqrt(30) folded so stage-2 matmul needs no extra scale.
    float x0[WDT][3];
    #pragma unroll
    for (int j = 0; j < WDT; ++j) {
        float4v lw = *(const float4v*)(wl + 200 + 4 * j);
        float c0 = lw[0] * v0; c0 = fmaf(lw[1], v3, c0); c0 = fmaf(lw[2], v6, c0);
        float c1 = lw[0] * v1; c1 = fmaf(lw[1], v4, c1); c1 = fmaf(lw[2], v7, c1);
        float c2 = lw[0] * v2; c2 = fmaf(lw[1], v5, c2); c2 = fmaf(lw[2], v8, c2);
        float n2u   = fmaf(c0, c0, fmaf(c1, c1, c2 * c2));
        float m     = fmaxf(n2u * k3sq, 1e-12f);   // ||y1||^2 clamped
        float inv_n = __builtin_amdgcn_rsqf(m);
        float n     = m * inv_n;                   // sqrt(m)
        float t     = fast_tanh(n + wl[360 + j]);
        float f     = t * inv_n * k3k10;
        x0[j][0] = c0 * f; x0[j][1] = c1 * f; x0[j][2] = c2 * f;
    }

    // ---- equivariant stage 2: lin1 + NormActivation + gate + final linear
    float acc0 = 0.f, acc1 = 0.f, acc2 = 0.f;
    #pragma unroll
    for (int j = 0; j < WDT; ++j) {
        const float* r = wl + 240 + 12 * j;
        float4v a0 = *(const float4v*)(r);
        float4v a1 = *(const float4v*)(r + 4);
        float4v a2 = *(const float4v*)(r + 8);
        float c0 = 0.f, c1 = 0.f, c2 = 0.f;
        #pragma unroll
        for (int u = 0; u < WDT; ++u) {
            float wt = (u < 4) ? a0[u] : (u < 8 ? a1[u - 4] : a2[u - 8]);
            c0 = fmaf(x0[u][0], wt, c0);
            c1 = fmaf(x0[u][1], wt, c1);
            c2 = fmaf(x0[u][2], wt, c2);
        }
        // c == reference y2v
        float m     = fmaxf(fmaf(c0, c0, fmaf(c1, c1, c2 * c2)), 1e-12f);
        float inv_n = __builtin_amdgcn_rsqf(m);
        float n     = m * inv_n;
        float t     = fast_tanh(n + wl[370 + j]);
        float g     = y2g[j] * t * inv_n * wl[380 + j];
        acc0 = fmaf(c0, g, acc0);
        acc1 = fmaf(c1, g, acc1);
        acc2 = fmaf(c2, g, acc2);
    }

    // ---- reduce 512 threads -> out[b][0..2]
    #pragma unroll
    for (int off = 32; off > 0; off >>= 1) {
        acc0 += __shfl_down(acc0, off, 64);
        acc1 += __shfl_down(acc1, off, 64);
        acc2 += __shfl_down(acc2, off, 64);
    }
    const int wave = tid >> 6;
    if ((tid & 63) == 0) { red[wave][0] = acc0; red[wave][1] = acc1; red[wave][2] = acc2; }
    __syncthreads();
    if (tid == 0) {
        float r0 = 0.f, r1 = 0.f, r2 = 0.f;
        #pragma unroll
        for (int wv = 0; wv < 8; ++wv) { r0 += red[wv][0]; r1 += red[wv][1]; r2 += red[wv][2]; }
        out[b * 3 + 0] = r0;
        out[b * 3 + 1] = r1;
        out[b * 3 + 2] = r2;
    }
}

extern "C" void kernel_launch(void* const* d_in, const int* in_sizes, int n_in,
                              void* d_out, int out_size, void* d_ws, size_t ws_size,
                              hipStream_t stream) {
    const float* invar   = (const float*)d_in[0];
    const float* vectors = (const float*)d_in[1];
    const float* w1_0    = (const float*)d_in[2];
    const float* b1_0    = (const float*)d_in[3];
    const float* w1_1    = (const float*)d_in[4];
    const float* b1_1    = (const float*)d_in[5];
    const float* lin0_w  = (const float*)d_in[6];
    const float* na0_b   = (const float*)d_in[7];
    const float* lin1_w  = (const float*)d_in[8];
    const float* na1_b   = (const float*)d_in[9];
    const float* final_w = (const float*)d_in[10];
    float* out = (float*)d_out;

    frc_2b_kernel<<<BB, 512, 0, stream>>>(invar, vectors, w1_0, b1_0, w1_1, b1_1,
                                          lin0_w, na0_b, lin1_w, na1_b, final_w, out);
}

// Round 6
// 173.615 us; speedup vs baseline: 1.5812x; 1.0282x over previous
//
#include <hip/hip_runtime.h>
#include <math.h>

#define BB 4096
#define PP 512
#define WDT 10

typedef float float2v __attribute__((ext_vector_type(2)));
typedef float float4v __attribute__((ext_vector_type(4)));

#define PKFMA(a, b, c) __builtin_elementwise_fma(a, b, c)
#define PKMAX(a, b)    __builtin_elementwise_max(a, b)

__device__ __forceinline__ float2v bc2(float s) { return (float2v){s, s}; }

// tanh(x) = 1 - 2/(exp2(2*log2e*x)+1); inf-safe without clamps.
__device__ __forceinline__ float fast_tanh(float x) {
    float e = __builtin_amdgcn_exp2f(x * 2.8853900817779268f); // v_exp_f32
    return 1.0f - 2.0f * __builtin_amdgcn_rcpf(e + 1.0f);      // v_rcp_f32
}

// LDS weight layout (floats), matrices in ORIGINAL [k][j] layout, rows padded
// to 16 floats so j-pairs are 8B-aligned and float4 row loads are 16B-aligned.
//   [0,80)    w1_0  5 rows x 16
//   [80,240)  w1_1  10 rows x 16
//   [240,288) lin0  3 rows x 16
//   [288,448) lin1  10 rows x 16
//   [448)     b1_0[10]  [464) b1_1[10]  [480) na0_b[10]  [496) na1_b[10]
//   [512)     final_w*1/sqrt(10) [10]   -> total 528
__global__ __launch_bounds__(512, 2) void frc_2b_kernel(
    const float* __restrict__ invar,    // [B,P,5]
    const float* __restrict__ vectors,  // [B,P,9]
    const float* __restrict__ w1_0,     // [5,10]
    const float* __restrict__ b1_0,     // [10]
    const float* __restrict__ w1_1,     // [10,10]
    const float* __restrict__ b1_1,     // [10]
    const float* __restrict__ lin0_w,   // [3,10]
    const float* __restrict__ na0_b,    // [10]
    const float* __restrict__ lin1_w,   // [10,10]
    const float* __restrict__ na1_b,    // [10]
    const float* __restrict__ final_w,  // [10,1]
    float* __restrict__ out)            // [B,3]
{
    __shared__ __align__(16) float wl[528];
    __shared__ float red[8][3];

    const int b   = blockIdx.x;
    const int tid = threadIdx.x;

    // ---- stage weights into LDS (padded [k][16] rows)
    for (int t = tid; t < 528; t += 512) {
        float val = 0.f;
        if (t < 80) {
            int i = t >> 4, j = t & 15;
            if (j < WDT) val = w1_0[i * WDT + j];
        } else if (t < 240) {
            int u = t - 80, i = u >> 4, j = u & 15;
            if (j < WDT) val = w1_1[i * WDT + j];
        } else if (t < 288) {
            int u = t - 240, i = u >> 4, j = u & 15;
            if (j < WDT) val = lin0_w[i * WDT + j];
        } else if (t < 448) {
            int u = t - 288, i = u >> 4, j = u & 15;
            if (j < WDT) val = lin1_w[i * WDT + j];
        } else if (t < 464) {
            int u = t - 448; if (u < WDT) val = b1_0[u];
        } else if (t < 480) {
            int u = t - 464; if (u < WDT) val = b1_1[u];
        } else if (t < 496) {
            int u = t - 480; if (u < WDT) val = na0_b[u];
        } else if (t < 512) {
            int u = t - 496; if (u < WDT) val = na1_b[u];
        } else {
            int u = t - 512; if (u < WDT) val = final_w[u] * 0.31622776601683794f;
        }
        wl[t] = val;
    }

    // ---- this thread's inputs (issued before the barrier to overlap)
    const float* iv = invar   + ((size_t)b * PP + tid) * 5;
    const float* vv = vectors + ((size_t)b * PP + tid) * 9;
    float in5a[5];
    #pragma unroll
    for (int i = 0; i < 5; ++i) in5a[i] = iv[i];
    float v[9];
    #pragma unroll
    for (int i = 0; i < 9; ++i) v[i] = vv[i];

    __syncthreads();

    const float k3sq  = 0.33333333333333333f;   // (1/sqrt3)^2
    const float k3k10 = 0.18257418583505536f;   // 1/sqrt(30)
    const float2v z2  = {0.f, 0.f};

    // ---- scalar branch L1: yp = relu(in5 @ w1_0 + b1_0), packed over j-pairs
    float2v yp[5];
    #pragma unroll
    for (int jp = 0; jp < 5; ++jp) yp[jp] = *(const float2v*)(wl + 448 + 2 * jp);
    #pragma unroll
    for (int i = 0; i < 5; ++i) {
        const float* r = wl + i * 16;
        float4v w03 = *(const float4v*)(r);
        float4v w47 = *(const float4v*)(r + 4);
        float2v w89 = *(const float2v*)(r + 8);
        float2v xb  = bc2(in5a[i]);
        yp[0] = PKFMA(__builtin_shufflevector(w03, w03, 0, 1), xb, yp[0]);
        yp[1] = PKFMA(__builtin_shufflevector(w03, w03, 2, 3), xb, yp[1]);
        yp[2] = PKFMA(__builtin_shufflevector(w47, w47, 0, 1), xb, yp[2]);
        yp[3] = PKFMA(__builtin_shufflevector(w47, w47, 2, 3), xb, yp[3]);
        yp[4] = PKFMA(w89, xb, yp[4]);
    }
    #pragma unroll
    for (int jp = 0; jp < 5; ++jp) yp[jp] = PKMAX(yp[jp], z2);

    // ---- scalar branch L2: y2p = relu(y @ w1_1 + b1_1)
    float2v y2p[5];
    #pragma unroll
    for (int jp = 0; jp < 5; ++jp) y2p[jp] = *(const float2v*)(wl + 464 + 2 * jp);
    #pragma unroll
    for (int k = 0; k < WDT; ++k) {
        const float* r = wl + 80 + k * 16;
        float4v w03 = *(const float4v*)(r);
        float4v w47 = *(const float4v*)(r + 4);
        float2v w89 = *(const float2v*)(r + 8);
        float2v xb  = bc2(yp[k >> 1][k & 1]);
        y2p[0] = PKFMA(__builtin_shufflevector(w03, w03, 0, 1), xb, y2p[0]);
        y2p[1] = PKFMA(__builtin_shufflevector(w03, w03, 2, 3), xb, y2p[1]);
        y2p[2] = PKFMA(__builtin_shufflevector(w47, w47, 0, 1), xb, y2p[2]);
        y2p[3] = PKFMA(__builtin_shufflevector(w47, w47, 2, 3), xb, y2p[3]);
        y2p[4] = PKFMA(w89, xb, y2p[4]);
    }
    #pragma unroll
    for (int jp = 0; jp < 5; ++jp) y2p[jp] = PKMAX(y2p[jp], z2);

    // ---- equivariant stage 1: lin0 + NormActivation (packed over j-pairs)
    float2v c0p[5], c1p[5], c2p[5];
    #pragma unroll
    for (int jp = 0; jp < 5; ++jp) { c0p[jp] = z2; c1p[jp] = z2; c2p[jp] = z2; }
    #pragma unroll
    for (int u = 0; u < 3; ++u) {
        const float* r = wl + 240 + u * 16;
        float4v w03 = *(const float4v*)(r);
        float4v w47 = *(const float4v*)(r + 4);
        float2v w89 = *(const float2v*)(r + 8);
        float2v wp[5] = {__builtin_shufflevector(w03, w03, 0, 1),
                         __builtin_shufflevector(w03, w03, 2, 3),
                         __builtin_shufflevector(w47, w47, 0, 1),
                         __builtin_shufflevector(w47, w47, 2, 3),
                         w89};
        float2v b0 = bc2(v[u * 3 + 0]), b1 = bc2(v[u * 3 + 1]), b2 = bc2(v[u * 3 + 2]);
        #pragma unroll
        for (int jp = 0; jp < 5; ++jp) {
            c0p[jp] = PKFMA(wp[jp], b0, c0p[jp]);
            c1p[jp] = PKFMA(wp[jp], b1, c1p[jp]);
            c2p[jp] = PKFMA(wp[jp], b2, c2p[jp]);
        }
    }
    // x0 stored with 1/sqrt(30) folded in
    float2v x0p[5], x1p[5], x2p[5];
    #pragma unroll
    for (int jp = 0; jp < 5; ++jp) {
        float2v n2p = PKFMA(c0p[jp], c0p[jp], PKFMA(c1p[jp], c1p[jp], c2p[jp] * c2p[jp]));
        float2v mp  = PKMAX(n2p * bc2(k3sq), bc2(1e-12f));
        float2v nab = *(const float2v*)(wl + 480 + 2 * jp);
        float fh[2];
        #pragma unroll
        for (int h = 0; h < 2; ++h) {
            float m     = mp[h];
            float inv_n = __builtin_amdgcn_rsqf(m);
            float n     = m * inv_n;
            float t     = fast_tanh(n + nab[h]);
            fh[h] = t * inv_n * k3k10;
        }
        float2v fp = {fh[0], fh[1]};
        x0p[jp] = c0p[jp] * fp;
        x1p[jp] = c1p[jp] * fp;
        x2p[jp] = c2p[jp] * fp;
    }

    // ---- equivariant stage 2: lin1 + NormActivation + gate + final linear
    float2v e0p[5], e1p[5], e2p[5];
    #pragma unroll
    for (int jp = 0; jp < 5; ++jp) { e0p[jp] = z2; e1p[jp] = z2; e2p[jp] = z2; }
    #pragma unroll
    for (int u = 0; u < WDT; ++u) {
        const float* r = wl + 288 + u * 16;
        float4v w03 = *(const float4v*)(r);
        float4v w47 = *(const float4v*)(r + 4);
        float2v w89 = *(const float2v*)(r + 8);
        float2v wp[5] = {__builtin_shufflevector(w03, w03, 0, 1),
                         __builtin_shufflevector(w03, w03, 2, 3),
                         __builtin_shufflevector(w47, w47, 0, 1),
                         __builtin_shufflevector(w47, w47, 2, 3),
                         w89};
        float2v b0 = bc2(x0p[u >> 1][u & 1]);
        float2v b1 = bc2(x1p[u >> 1][u & 1]);
        float2v b2 = bc2(x2p[u >> 1][u & 1]);
        #pragma unroll
        for (int jp = 0; jp < 5; ++jp) {
            e0p[jp] = PKFMA(wp[jp], b0, e0p[jp]);
            e1p[jp] = PKFMA(wp[jp], b1, e1p[jp]);
            e2p[jp] = PKFMA(wp[jp], b2, e2p[jp]);
        }
    }
    float2v a0p = z2, a1p = z2, a2p = z2;
    #pragma unroll
    for (int jp = 0; jp < 5; ++jp) {
        // e == reference y2v (scales folded upstream)
        float2v n2p = PKFMA(e0p[jp], e0p[jp], PKFMA(e1p[jp], e1p[jp], e2p[jp] * e2p[jp]));
        float2v mp  = PKMAX(n2p, bc2(1e-12f));
        float2v nab = *(const float2v*)(wl + 496 + 2 * jp);
        float2v fwp = *(const float2v*)(wl + 512 + 2 * jp);
        float gh[2];
        #pragma unroll
        for (int h = 0; h < 2; ++h) {
            float m     = mp[h];
            float inv_n = __builtin_amdgcn_rsqf(m);
            float n     = m * inv_n;
            float t     = fast_tanh(n + nab[h]);
            gh[h] = y2p[jp][h] * t * inv_n * fwp[h];
        }
        float2v gp = {gh[0], gh[1]};
        a0p = PKFMA(e0p[jp], gp, a0p);
        a1p = PKFMA(e1p[jp], gp, a1p);
        a2p = PKFMA(e2p[jp], gp, a2p);
    }
    float acc0 = a0p[0] + a0p[1];
    float acc1 = a1p[0] + a1p[1];
    float acc2 = a2p[0] + a2p[1];

    // ---- reduce 512 threads -> out[b][0..2]
    #pragma unroll
    for (int off = 32; off > 0; off >>= 1) {
        acc0 += __shfl_down(acc0, off, 64);
        acc1 += __shfl_down(acc1, off, 64);
        acc2 += __shfl_down(acc2, off, 64);
    }
    const int wave = tid >> 6;
    if ((tid & 63) == 0) { red[wave][0] = acc0; red[wave][1] = acc1; red[wave][2] = acc2; }
    __syncthreads();
    if (tid == 0) {
        float r0 = 0.f, r1 = 0.f, r2 = 0.f;
        #pragma unroll
        for (int wv = 0; wv < 8; ++wv) { r0 += red[wv][0]; r1 += red[wv][1]; r2 += red[wv][2]; }
        out[b * 3 + 0] = r0;
        out[b * 3 + 1] = r1;
        out[b * 3 + 2] = r2;
    }
}

extern "C" void kernel_launch(void* const* d_in, const int* in_sizes, int n_in,
                              void* d_out, int out_size, void* d_ws, size_t ws_size,
                              hipStream_t stream) {
    const float* invar   = (const float*)d_in[0];
    const float* vectors = (const float*)d_in[1];
    const float* w1_0    = (const float*)d_in[2];
    const float* b1_0    = (const float*)d_in[3];
    const float* w1_1    = (const float*)d_in[4];
    const float* b1_1    = (const float*)d_in[5];
    const float* lin0_w  = (const float*)d_in[6];
    const float* na0_b   = (const float*)d_in[7];
    const float* lin1_w  = (const float*)d_in[8];
    const float* na1_b   = (const float*)d_in[9];
    const float* final_w = (const float*)d_in[10];
    float* out = (float*)d_out;

    frc_2b_kernel<<<BB, 512, 0, stream>>>(invar, vectors, w1_0, b1_0, w1_1, b1_1,
                                          lin0_w, na0_b, lin1_w, na1_b, final_w, out);
}

// Round 7
// 165.840 us; speedup vs baseline: 1.6554x; 1.0469x over previous
//
#include <hip/hip_runtime.h>
#include <math.h>

#define BB 4096
#define PP 512
#define WDT 10

typedef float float2v __attribute__((ext_vector_type(2)));

#define PKFMA(a, b, c) __builtin_elementwise_fma(a, b, c)
#define PKMAX(a, b)    __builtin_elementwise_max(a, b)
#define FENCE()        __builtin_amdgcn_sched_barrier(0)

__device__ __forceinline__ float2v bc2(float s) { return (float2v){s, s}; }

// tanh(x) = 1 - 2/(exp2(2*log2e*x)+1); inf-safe without clamps.
__device__ __forceinline__ float fast_tanh(float x) {
    float e = __builtin_amdgcn_exp2f(x * 2.8853900817779268f); // v_exp_f32
    return 1.0f - 2.0f * __builtin_amdgcn_rcpf(e + 1.0f);      // v_rcp_f32
}

// All weights are wave-uniform with compile-time offsets -> s_load into SGPRs.
// Uniform working set is PHASED (k-row halves, <=50 weight floats live) with
// sched_barrier(0) fences so the compiler never spills SGPRs (R1/R3 lesson).
__global__ __launch_bounds__(512) void frc_2b_kernel(
    const float* __restrict__ invar,    // [B,P,5]
    const float* __restrict__ vectors,  // [B,P,9]
    const float* __restrict__ w1_0,     // [5,10]
    const float* __restrict__ b1_0,     // [10]
    const float* __restrict__ w1_1,     // [10,10]
    const float* __restrict__ b1_1,     // [10]
    const float* __restrict__ lin0_w,   // [3,10]
    const float* __restrict__ na0_b,    // [10]
    const float* __restrict__ lin1_w,   // [10,10]
    const float* __restrict__ na1_b,    // [10]
    const float* __restrict__ final_w,  // [10,1]
    float* __restrict__ out)            // [B,3]
{
    __shared__ float red[8][3];

    const int b   = blockIdx.x;
    const int tid = threadIdx.x;

    // ---- per-lane inputs (issued first; VMEM latency hides under s_loads)
    const float* iv = invar   + ((size_t)b * PP + tid) * 5;
    const float* vv = vectors + ((size_t)b * PP + tid) * 9;
    float in5a[5];
    #pragma unroll
    for (int i = 0; i < 5; ++i) in5a[i] = iv[i];
    float v[9];
    #pragma unroll
    for (int i = 0; i < 9; ++i) v[i] = vv[i];

    const float k3sq  = 0.33333333333333333f;   // (1/sqrt3)^2
    const float k3k10 = 0.18257418583505536f;   // 1/sqrt(30)
    const float k10   = 0.31622776601683794f;   // 1/sqrt(10)
    const float2v z2  = {0.f, 0.f};

    // ================= Phase 1: L1  y = relu(in5 @ w1_0 + b1_0)
    float2v yp[5];
    #pragma unroll
    for (int jp = 0; jp < 5; ++jp) yp[jp] = *(const float2v*)(b1_0 + 2 * jp);
    #pragma unroll
    for (int i = 0; i < 5; ++i) {
        const float2v xb = bc2(in5a[i]);
        #pragma unroll
        for (int jp = 0; jp < 5; ++jp) {
            float2v wp = *(const float2v*)(w1_0 + i * WDT + 2 * jp);
            yp[jp] = PKFMA(wp, xb, yp[jp]);
        }
    }
    #pragma unroll
    for (int jp = 0; jp < 5; ++jp) yp[jp] = PKMAX(yp[jp], z2);
    FENCE();

    // ================= Phase 2: L2  y2 = relu(y @ w1_1 + b1_1), k-halves
    float2v y2p[5];
    #pragma unroll
    for (int jp = 0; jp < 5; ++jp) y2p[jp] = *(const float2v*)(b1_1 + 2 * jp);
    #pragma unroll
    for (int k = 0; k < 5; ++k) {
        const float2v xb = bc2(yp[k >> 1][k & 1]);
        #pragma unroll
        for (int jp = 0; jp < 5; ++jp) {
            float2v wp = *(const float2v*)(w1_1 + k * WDT + 2 * jp);
            y2p[jp] = PKFMA(wp, xb, y2p[jp]);
        }
    }
    FENCE();
    #pragma unroll
    for (int k = 5; k < WDT; ++k) {
        const float2v xb = bc2(yp[k >> 1][k & 1]);
        #pragma unroll
        for (int jp = 0; jp < 5; ++jp) {
            float2v wp = *(const float2v*)(w1_1 + k * WDT + 2 * jp);
            y2p[jp] = PKFMA(wp, xb, y2p[jp]);
        }
    }
    #pragma unroll
    for (int jp = 0; jp < 5; ++jp) y2p[jp] = PKMAX(y2p[jp], z2);
    FENCE();

    // ================= Phase 3: lin0 + NormActivation
    float2v c0p[5], c1p[5], c2p[5];
    #pragma unroll
    for (int jp = 0; jp < 5; ++jp) { c0p[jp] = z2; c1p[jp] = z2; c2p[jp] = z2; }
    #pragma unroll
    for (int u = 0; u < 3; ++u) {
        const float2v b0 = bc2(v[u * 3 + 0]);
        const float2v b1 = bc2(v[u * 3 + 1]);
        const float2v b2 = bc2(v[u * 3 + 2]);
        #pragma unroll
        for (int jp = 0; jp < 5; ++jp) {
            float2v wp = *(const float2v*)(lin0_w + u * WDT + 2 * jp);
            c0p[jp] = PKFMA(wp, b0, c0p[jp]);
            c1p[jp] = PKFMA(wp, b1, c1p[jp]);
            c2p[jp] = PKFMA(wp, b2, c2p[jp]);
        }
    }
    // x0 stored with 1/sqrt(30) folded in
    float2v x0p[5], x1p[5], x2p[5];
    #pragma unroll
    for (int jp = 0; jp < 5; ++jp) {
        float2v n2p = PKFMA(c0p[jp], c0p[jp], PKFMA(c1p[jp], c1p[jp], c2p[jp] * c2p[jp]));
        float2v mp  = PKMAX(n2p * bc2(k3sq), bc2(1e-12f));
        float2v nab = *(const float2v*)(na0_b + 2 * jp);
        float fh[2];
        #pragma unroll
        for (int h = 0; h < 2; ++h) {
            float m     = mp[h];
            float inv_n = __builtin_amdgcn_rsqf(m);
            float n     = m * inv_n;
            float t     = fast_tanh(n + nab[h]);
            fh[h] = t * inv_n * k3k10;
        }
        float2v fp = {fh[0], fh[1]};
        x0p[jp] = c0p[jp] * fp;
        x1p[jp] = c1p[jp] * fp;
        x2p[jp] = c2p[jp] * fp;
    }
    FENCE();

    // ================= Phase 4: lin1 (k-halves) + NormActivation + gate + final
    float2v e0p[5], e1p[5], e2p[5];
    #pragma unroll
    for (int jp = 0; jp < 5; ++jp) { e0p[jp] = z2; e1p[jp] = z2; e2p[jp] = z2; }
    #pragma unroll
    for (int u = 0; u < 5; ++u) {
        const float2v b0 = bc2(x0p[u >> 1][u & 1]);
        const float2v b1 = bc2(x1p[u >> 1][u & 1]);
        const float2v b2 = bc2(x2p[u >> 1][u & 1]);
        #pragma unroll
        for (int jp = 0; jp < 5; ++jp) {
            float2v wp = *(const float2v*)(lin1_w + u * WDT + 2 * jp);
            e0p[jp] = PKFMA(wp, b0, e0p[jp]);
            e1p[jp] = PKFMA(wp, b1, e1p[jp]);
            e2p[jp] = PKFMA(wp, b2, e2p[jp]);
        }
    }
    FENCE();
    #pragma unroll
    for (int u = 5; u < WDT; ++u) {
        const float2v b0 = bc2(x0p[u >> 1][u & 1]);
        const float2v b1 = bc2(x1p[u >> 1][u & 1]);
        const float2v b2 = bc2(x2p[u >> 1][u & 1]);
        #pragma unroll
        for (int jp = 0; jp < 5; ++jp) {
            float2v wp = *(const float2v*)(lin1_w + u * WDT + 2 * jp);
            e0p[jp] = PKFMA(wp, b0, e0p[jp]);
            e1p[jp] = PKFMA(wp, b1, e1p[jp]);
            e2p[jp] = PKFMA(wp, b2, e2p[jp]);
        }
    }
    FENCE();

    float2v a0p = z2, a1p = z2, a2p = z2;
    #pragma unroll
    for (int jp = 0; jp < 5; ++jp) {
        // e == reference y2v (scales folded upstream)
        float2v n2p = PKFMA(e0p[jp], e0p[jp], PKFMA(e1p[jp], e1p[jp], e2p[jp] * e2p[jp]));
        float2v mp  = PKMAX(n2p, bc2(1e-12f));
        float2v nab = *(const float2v*)(na1_b + 2 * jp);
        float2v fwp = *(const float2v*)(final_w + 2 * jp);
        float gh[2];
        #pragma unroll
        for (int h = 0; h < 2; ++h) {
            float m     = mp[h];
            float inv_n = __builtin_amdgcn_rsqf(m);
            float n     = m * inv_n;
            float t     = fast_tanh(n + nab[h]);
            gh[h] = y2p[jp][h] * t * inv_n * fwp[h];
        }
        float2v gp = {gh[0], gh[1]};
        a0p = PKFMA(e0p[jp], gp, a0p);
        a1p = PKFMA(e1p[jp], gp, a1p);
        a2p = PKFMA(e2p[jp], gp, a2p);
    }
    // final 1/sqrt(10) pulled out of the j-sum (linear)
    float acc0 = (a0p[0] + a0p[1]) * k10;
    float acc1 = (a1p[0] + a1p[1]) * k10;
    float acc2 = (a2p[0] + a2p[1]) * k10;

    // ---- reduce 512 threads -> out[b][0..2]
    #pragma unroll
    for (int off = 32; off > 0; off >>= 1) {
        acc0 += __shfl_down(acc0, off, 64);
        acc1 += __shfl_down(acc1, off, 64);
        acc2 += __shfl_down(acc2, off, 64);
    }
    const int wave = tid >> 6;
    if ((tid & 63) == 0) { red[wave][0] = acc0; red[wave][1] = acc1; red[wave][2] = acc2; }
    __syncthreads();
    if (tid == 0) {
        float r0 = 0.f, r1 = 0.f, r2 = 0.f;
        #pragma unroll
        for (int wv = 0; wv < 8; ++wv) { r0 += red[wv][0]; r1 += red[wv][1]; r2 += red[wv][2]; }
        out[b * 3 + 0] = r0;
        out[b * 3 + 1] = r1;
        out[b * 3 + 2] = r2;
    }
}

extern "C" void kernel_launch(void* const* d_in, const int* in_sizes, int n_in,
                              void* d_out, int out_size, void* d_ws, size_t ws_size,
                              hipStream_t stream) {
    const float* invar   = (const float*)d_in[0];
    const float* vectors = (const float*)d_in[1];
    const float* w1_0    = (const float*)d_in[2];
    const float* b1_0    = (const float*)d_in[3];
    const float* w1_1    = (const float*)d_in[4];
    const float* b1_1    = (const float*)d_in[5];
    const float* lin0_w  = (const float*)d_in[6];
    const float* na0_b   = (const float*)d_in[7];
    const float* lin1_w  = (const float*)d_in[8];
    const float* na1_b   = (const float*)d_in[9];
    const float* final_w = (const float*)d_in[10];
    float* out = (float*)d_out;

    frc_2b_kernel<<<BB, 512, 0, stream>>>(invar, vectors, w1_0, b1_0, w1_1, b1_1,
                                          lin0_w, na0_b, lin1_w, na1_b, final_w, out);
}